// Round 5
// baseline (222.125 us; speedup 1.0000x reference)
//
#include <hip/hip_runtime.h>
#include <hip/hip_bf16.h>
#include <math.h>

// Problem constants
#define T_TOK 8192   // B*S tokens
#define DIM   512    // D
#define NEXP  8      // E
#define HID   2048   // H
#define NBAT  8      // B
#define SEQ   1024   // S

typedef short  short8 __attribute__((ext_vector_type(8)));
typedef float  f32x4  __attribute__((ext_vector_type(4)));

__device__ __forceinline__ unsigned short f2bf(float f) {
    union { float f; unsigned int u; } v; v.f = f;
    unsigned int u = v.u;
    unsigned int r = u + 0x7FFFu + ((u >> 16) & 1u);  // RNE
    return (unsigned short)(r >> 16);
}

// tanh-approx gelu via single v_exp_f32: v * sigmoid(1.59577*(v + 0.044715 v^3))
__device__ __forceinline__ float gelu_f(float v) {
    float v2 = v * v;
    float w = v * (-2.302344f - 0.102955f * v2);   // -log2(e)*1.59577*(1 + 0.044715 v^2)
    return v / (1.f + __builtin_amdgcn_exp2f(w));
}

// ---------------- fused prep + gate ----
// w1f layout (fragment-direct): [E][G=128 hgrps of 16][KK=16 ksteps of 32][512 ushorts]
// block (e,g,kk): element (q*16+c)*8+j  =  w1[e][d=kk*32+q*8+j][h=g*16+c]
// -> GEMM lane (quad,col) reads its MFMA B-fragment at offset lane*8 (16B), fully coalesced.
__global__ void prep_gate_k(const float* __restrict__ w1, unsigned short* __restrict__ w1f,
                            const float* __restrict__ w2, const float* __restrict__ b2,
                            float* __restrict__ w2sum, float* __restrict__ b2sum,
                            int* __restrict__ counts,
                            const float* __restrict__ x, const float* __restrict__ gw,
                            const float* __restrict__ gb,
                            unsigned short* __restrict__ xb,
                            int* __restrict__ eidx, float* __restrict__ esc0,
                            float* __restrict__ esc1) {
    int bid = blockIdx.x;
    int tid = threadIdx.x;
    int wave = tid >> 6, lane = tid & 63;
    if (bid < 2048) {
        // ---- w1 [E][D][H] fp32 -> w1f fragment-direct bf16 ----
        __shared__ unsigned short tile[64][68];   // [hLocal][dLocal]
        int e = bid >> 8, r = bid & 255;
        int d0 = (r & 7) * 64, h0 = (r >> 3) * 64;
        const float* src = w1 + (size_t)e * DIM * HID;
        #pragma unroll
        for (int pass = 0; pass < 4; ++pass) {
            int dr = pass * 16 + (tid >> 4);
            int hc = (tid & 15) * 4;
            float4 v = *(const float4*)(src + (size_t)(d0 + dr) * HID + h0 + hc);
            tile[hc + 0][dr] = f2bf(v.x);
            tile[hc + 1][dr] = f2bf(v.y);
            tile[hc + 2][dr] = f2bf(v.z);
            tile[hc + 3][dr] = f2bf(v.w);
        }
        __syncthreads();
        // this 64x64 region covers ksteps {kk0,kk0+1} and hgrps {g0..g0+3}
        int l = tid & 63, q = l >> 4, c = l & 15;
        int kk0 = (r & 7) * 2, g0 = (r >> 3) * 4;
        #pragma unroll
        for (int pi = 0; pi < 2; ++pi) {
            int sub = pi * 4 + wave;            // 0..7
            int kk2 = sub >> 2, g2 = sub & 3;
            const unsigned short* tp = &tile[g2 * 16 + c][kk2 * 32 + q * 8];
            ushort4 a = *(const ushort4*)(tp);
            ushort4 b = *(const ushort4*)(tp + 4);
            unsigned short* dst = w1f +
                ((size_t)(e * 128 + g0 + g2) * 16 + kk0 + kk2) * 512 + l * 8;
            *(ushort4*)(dst)     = a;
            *(ushort4*)(dst + 4) = b;
        }
    } else if (bid < 4096) {
        // ---- gating + fused x->bf16 cast (one token per wave) ----
        int t = (bid - 2048) * 4 + wave;
        const float* xp = x + (size_t)t * DIM;
        unsigned short* xbp = xb + (size_t)t * DIM;
        float acc[8] = {0, 0, 0, 0, 0, 0, 0, 0};
        #pragma unroll
        for (int it = 0; it < 8; ++it) {
            int d = it * 64 + lane;
            float xv = xp[d];
            xbp[d] = f2bf(xv);
            float4 g0 = *(const float4*)(gw + d * 8);
            float4 g1 = *(const float4*)(gw + d * 8 + 4);
            acc[0] += xv * g0.x; acc[1] += xv * g0.y; acc[2] += xv * g0.z; acc[3] += xv * g0.w;
            acc[4] += xv * g1.x; acc[5] += xv * g1.y; acc[6] += xv * g1.z; acc[7] += xv * g1.w;
        }
        #pragma unroll
        for (int e = 0; e < 8; ++e) {
            float s = acc[e];
            #pragma unroll
            for (int off = 32; off >= 1; off >>= 1) s += __shfl_xor(s, off);
            acc[e] = s + gb[e];
        }
        float v0 = -1e30f, v1 = -1e30f; int i0 = 0, i1 = 0;
        #pragma unroll
        for (int e = 0; e < 8; ++e) {
            float v = acc[e];
            if (v > v0) { v1 = v0; i1 = i0; v0 = v; i0 = e; }
            else if (v > v1) { v1 = v; i1 = e; }
        }
        float e1 = expf(v1 - v0);
        float inv = 1.f / (1.f + e1);
        if (lane == 0) {
            eidx[t] = i0 | (i1 << 4);
            esc0[t] = inv;
            esc1[t] = e1 * inv;
        }
    } else if (bid < 8192) {
        // ---- w2sum: row-sums of w2 ----
        int row = (bid - 4096) * 4 + wave;
        const float* p = w2 + (size_t)row * DIM;
        float4 a = *(const float4*)(p + lane * 4);
        float4 b = *(const float4*)(p + 256 + lane * 4);
        float s = a.x + a.y + a.z + a.w + b.x + b.y + b.z + b.w;
        #pragma unroll
        for (int off = 32; off >= 1; off >>= 1) s += __shfl_xor(s, off);
        if (lane == 0) w2sum[row] = s;
    } else {
        if (tid < 8) counts[tid] = 0;
        for (int r = wave; r < NEXP; r += 4) {
            const float* p = b2 + (size_t)r * DIM;
            float s = 0.f;
            for (int i = lane; i < DIM; i += 64) s += p[i];
            #pragma unroll
            for (int off = 32; off >= 1; off >>= 1) s += __shfl_xor(s, off);
            if (lane == 0) b2sum[r] = s;
        }
    }
}

// ---------------- routing: ballot-rank within wave, LDS across waves, 8 atomics/block ----------------
__global__ __launch_bounds__(1024) void route_k(
    const int* __restrict__ eidx, const float* __restrict__ esc0,
    const float* __restrict__ esc1, const float* __restrict__ b2sum,
    int* __restrict__ counts,
    int* __restrict__ ptok, float* __restrict__ pscore,
    float* __restrict__ s_partial) {
    int tid = threadIdx.x;
    int t = blockIdx.x * 1024 + tid;
    int wv = tid >> 6, lane = tid & 63;
    int pk = eidx[t];
    int i0 = pk & 0xf, i1 = (pk >> 4) & 0xf;
    float s0 = esc0[t], s1 = esc1[t];

    s_partial[t] = s0 * b2sum[i0] + s1 * b2sum[i1];

    __shared__ int waveCnt[16][8];
    __shared__ int waveBase[16][8];

    unsigned long long m0[8], m1[8];
    #pragma unroll
    for (int e = 0; e < 8; ++e) {
        m0[e] = __ballot(i0 == e);
        m1[e] = __ballot(i1 == e);
    }
    if (lane < 8) {
        int c = 0;
        #pragma unroll
        for (int e = 0; e < 8; ++e)
            if (lane == e) c = __popcll(m0[e]) + __popcll(m1[e]);
        waveCnt[wv][lane] = c;
    }
    __syncthreads();
    if (tid < 8) {
        int e = tid;
        int total = 0;
        #pragma unroll
        for (int w = 0; w < 16; ++w) total += waveCnt[w][e];
        int base = atomicAdd(&counts[e], total);
        int run = base;
        #pragma unroll
        for (int w = 0; w < 16; ++w) {
            waveBase[w][e] = run;
            run += waveCnt[w][e];
        }
    }
    __syncthreads();

    unsigned long long lt = (1ULL << lane) - 1ULL;
    int slot0 = 0, slot1 = 0;
    #pragma unroll
    for (int e = 0; e < 8; ++e) {
        if (i0 == e) slot0 = waveBase[wv][e] + __popcll(m0[e] & lt);
        if (i1 == e) slot1 = waveBase[wv][e] + __popcll(m0[e]) + __popcll(m1[e] & lt);
    }
    ptok[i0 * T_TOK + slot0] = t;  pscore[i0 * T_TOK + slot0] = s0;
    ptok[i1 * T_TOK + slot1] = t;  pscore[i1 * T_TOK + slot1] = s1;
}

// ---------------- grouped GEMM: BK=64, A-only LDS dbuf, B global->VGPR, 1 barrier-pair/64K ----
// LDS = 2*16KB (A) + 1KB = 33KB -> 4 blocks/CU. 8 K-iterations, 32 MFMA per iteration per wave.
#define GPTR(p) (const __attribute__((address_space(1))) void*)(p)
#define LPTR(p) (__attribute__((address_space(3))) void*)(p)

__global__ __launch_bounds__(256, 4) void moe_gemm_k(
    const unsigned short* __restrict__ xb, const unsigned short* __restrict__ w1f,
    const float* __restrict__ b1, const float* __restrict__ w2sum,
    const int* __restrict__ counts, const int* __restrict__ ptok,
    const float* __restrict__ pscore, float* __restrict__ s_partial) {

    // XCD swizzle, hTile-pair ordering: xcd = flat&7 owns hTiles {2*xcd, 2*xcd+1};
    // consecutive blocks on an XCD share bx (A-tile L2 reuse); B slice 2MB < 4MB L2.
    int flat = blockIdx.x + (int)blockIdx.y * 135;
    int xcd = flat & 7;
    int s = flat >> 3;            // 0..269
    int bx = s >> 1;              // 0..134
    int hBase = (xcd * 2 + (s & 1)) * 128;

    // derive (expert, rowBase) from counts prefix
    int e = 8, rowBase = 0, accT = 0;
    #pragma unroll
    for (int i = 0; i < 8; ++i) {
        int nt = (counts[i] + 127) >> 7;
        if (e == 8 && bx < accT + nt) { e = i; rowBase = (bx - accT) * 128; }
        accT += nt;
    }
    if (e == 8) return;
    int n_e = counts[e];

    __shared__ unsigned short A_s[2][128 * 64];   // [buf][row][k], chunk-swizzled (round-1 geometry)
    __shared__ int   tokLds[128];
    __shared__ float scoreLds[128];

    int tid = threadIdx.x;
    int wave = tid >> 6, lane = tid & 63;

    if (tid < 128) {
        int r = rowBase + tid;
        bool valid = r < n_e;
        tokLds[tid]   = valid ? ptok[e * T_TOK + r]   : 0;
        scoreLds[tid] = valid ? pscore[e * T_TOK + r] : 0.f;
    }
    __syncthreads();

    // A staging: 1024 linear 16B chunks per 128x64 tile; 4 per thread.
    // chunk c: row=c>>3, pos=c&7, global k-piece j=(pos^(row&7))*8 (proven 0-conflict geometry).
    // 32-bit offsets -> saddr-form loads (VGPR-lean).
    unsigned gAo[4];
    #pragma unroll
    for (int i = 0; i < 4; ++i) {
        int c = i * 256 + tid;                  // 0..1023
        int row = c >> 3, pos = c & 7;
        int j = (pos ^ (row & 7)) * 8;
        gAo[i] = (unsigned)tokLds[row] * DIM + j;
    }

    int wm = wave >> 1, wn = wave & 1;
    int quad = lane >> 4, col = lane & 15;

    f32x4 acc[4][4];
    #pragma unroll
    for (int m = 0; m < 4; ++m)
        #pragma unroll
        for (int n = 0; n < 4; ++n)
            acc[m][n] = (f32x4){0.f, 0.f, 0.f, 0.f};

    // A read addressing (both k-halves), m-stride = 16 rows * 64 = 1024 ushorts
    int aOff0 = (wm * 64 + col) * 64 + ((((0 << 2) | quad) ^ (col & 7)) * 8);
    int aOff1 = (wm * 64 + col) * 64 + ((((1 << 2) | quad) ^ (col & 7)) * 8);

    // B: fragment-direct; frag n at hgrp (hBase>>4)+wn*4+n; k-sub s at +s*512
    const unsigned short* bp = w1f +
        (size_t)(e * 128 + (hBase >> 4) + wn * 4) * 8192 + lane * 8;
    short8 bf[4];

    // ---- prologue: stage A(0), A(1), load B(0,h0). Issue order pinned for vmcnt math.
    #pragma unroll
    for (int i = 0; i < 4; ++i)
        __builtin_amdgcn_global_load_lds(GPTR(xb + gAo[i]), LPTR(&A_s[0][i * 2048 + tid * 8]), 16, 0, 0);
    __builtin_amdgcn_sched_barrier(0);
    #pragma unroll
    for (int i = 0; i < 4; ++i)
        __builtin_amdgcn_global_load_lds(GPTR(xb + gAo[i] + 64), LPTR(&A_s[1][i * 2048 + tid * 8]), 16, 0, 0);
    __builtin_amdgcn_sched_barrier(0);
    #pragma unroll
    for (int n = 0; n < 4; ++n) bf[n] = *(const short8*)(bp + n * 8192);
    __builtin_amdgcn_sched_barrier(0);

    #pragma unroll
    for (int kk = 0; kk < 8; ++kk) {
        const int cur = kk & 1;
        // exact newer-than-A(kk) counts (issue-order pinned): {8,16,20,20,20,20,20,16}
        if (kk == 0)                 { asm volatile("s_waitcnt vmcnt(8)"  ::: "memory"); }
        else if (kk == 1 || kk == 7) { asm volatile("s_waitcnt vmcnt(16)" ::: "memory"); }
        else                         { asm volatile("s_waitcnt vmcnt(20)" ::: "memory"); }
        __builtin_amdgcn_s_barrier();

        // read BOTH k-halves of A before releasing the buffer (single barrier-pair per 64-K)
        short8 af0[4], af1[4];
        const unsigned short* aB = &A_s[cur][0];
        #pragma unroll
        for (int m = 0; m < 4; ++m) af0[m] = *(const short8*)(aB + aOff0 + m * 1024);
        #pragma unroll
        for (int m = 0; m < 4; ++m) af1[m] = *(const short8*)(aB + aOff1 + m * 1024);
        asm volatile("s_waitcnt lgkmcnt(0)" ::: "memory");
        __builtin_amdgcn_s_barrier();

        // stage A(kk+2) into the just-released buffer
        if (kk < 6) {
            int ko = (kk + 2) * 64;
            #pragma unroll
            for (int i = 0; i < 4; ++i)
                __builtin_amdgcn_global_load_lds(GPTR(xb + gAo[i] + ko), LPTR(&A_s[cur][i * 2048 + tid * 8]), 16, 0, 0);
        }
        __builtin_amdgcn_sched_barrier(0);      // pin stage ahead of MFMA cluster

        // half 0: MFMA with bf = B(kk, h0)
        __builtin_amdgcn_s_setprio(1);
        #pragma unroll
        for (int m = 0; m < 4; ++m)
            #pragma unroll
            for (int n = 0; n < 4; ++n)
                acc[m][n] = __builtin_amdgcn_mfma_f32_16x16x32_bf16(af0[m], bf[n], acc[m][n], 0, 0, 0);
        __builtin_amdgcn_s_setprio(0);

        // reload bf <- B(kk, h1); ~300cy L2 latency covered by half-0's MFMA pipe time
        #pragma unroll
        for (int n = 0; n < 4; ++n)
            bf[n] = *(const short8*)(bp + (2 * kk + 1) * 512 + n * 8192);

        // half 1
        __builtin_amdgcn_s_setprio(1);
        #pragma unroll
        for (int m = 0; m < 4; ++m)
            #pragma unroll
            for (int n = 0; n < 4; ++n)
                acc[m][n] = __builtin_amdgcn_mfma_f32_16x16x32_bf16(af1[m], bf[n], acc[m][n], 0, 0, 0);
        __builtin_amdgcn_s_setprio(0);

        // prefetch bf <- B(kk+1, h0) for next iteration (WAW/WAR on bf keeps order)
        if (kk < 7) {
            #pragma unroll
            for (int n = 0; n < 4; ++n)
                bf[n] = *(const short8*)(bp + (2 * kk + 2) * 512 + n * 8192);
        }
    }

    // epilogue: val = gelu(acc + b1[h]) * w2sum[h]; reduce over h; atomicAdd score*partial
    const float* b1e = b1 + e * HID;
    const float* w2e = w2sum + e * HID;
    float bias[4], wsum[4];
    #pragma unroll
    for (int n = 0; n < 4; ++n) {
        int h = hBase + wn * 64 + n * 16 + col;
        bias[n] = b1e[h];
        wsum[n] = w2e[h];
    }
    #pragma unroll
    for (int m = 0; m < 4; ++m) {
        float rp0 = 0.f, rp1 = 0.f, rp2 = 0.f, rp3 = 0.f;
        #pragma unroll
        for (int n = 0; n < 4; ++n) {
            rp0 += gelu_f(acc[m][n][0] + bias[n]) * wsum[n];
            rp1 += gelu_f(acc[m][n][1] + bias[n]) * wsum[n];
            rp2 += gelu_f(acc[m][n][2] + bias[n]) * wsum[n];
            rp3 += gelu_f(acc[m][n][3] + bias[n]) * wsum[n];
        }
        #pragma unroll
        for (int off = 8; off >= 1; off >>= 1) {
            rp0 += __shfl_xor(rp0, off);
            rp1 += __shfl_xor(rp1, off);
            rp2 += __shfl_xor(rp2, off);
            rp3 += __shfl_xor(rp3, off);
        }
        if (col < 4) {
            float mine = (col == 0) ? rp0 : (col == 1) ? rp1 : (col == 2) ? rp2 : rp3;
            int rl = wm * 64 + m * 16 + quad * 4 + col;
            int r = rowBase + rl;
            if (r < n_e)
                atomicAdd(&s_partial[tokLds[rl]], scoreLds[rl] * mine);
        }
    }
}

// ---------------- per-batch log_softmax over seq ----------------
__global__ void lsm_k(const float* __restrict__ s, float* __restrict__ out) {
    int b = blockIdx.x, tid = threadIdx.x;
    int wave = tid >> 6, lane = tid & 63;
    __shared__ float red[4];
    const float* sp = s + (size_t)b * SEQ;
    float v[4];
    #pragma unroll
    for (int i = 0; i < 4; ++i) v[i] = sp[tid + i * 256];
    float m = fmaxf(fmaxf(v[0], v[1]), fmaxf(v[2], v[3]));
    #pragma unroll
    for (int off = 32; off >= 1; off >>= 1) m = fmaxf(m, __shfl_xor(m, off));
    if (lane == 0) red[wave] = m;
    __syncthreads();
    m = fmaxf(fmaxf(red[0], red[1]), fmaxf(red[2], red[3]));
    __syncthreads();
    float t = 0.f;
    #pragma unroll
    for (int i = 0; i < 4; ++i) t += expf(v[i] - m);
    #pragma unroll
    for (int off = 32; off >= 1; off >>= 1) t += __shfl_xor(t, off);
    if (lane == 0) red[wave] = t;
    __syncthreads();
    t = red[0] + red[1] + red[2] + red[3];
    float L = m + logf(t);
    #pragma unroll
    for (int i = 0; i < 4; ++i) out[(size_t)b * SEQ + tid + i * 256] = v[i] - L;
}

extern "C" void kernel_launch(void* const* d_in, const int* in_sizes, int n_in,
                              void* d_out, int out_size, void* d_ws, size_t ws_size,
                              hipStream_t stream) {
    const float* x  = (const float*)d_in[0];
    const float* gw = (const float*)d_in[1];
    const float* gb = (const float*)d_in[2];
    const float* w1 = (const float*)d_in[3];
    const float* b1 = (const float*)d_in[4];
    const float* w2 = (const float*)d_in[5];
    const float* b2 = (const float*)d_in[6];
    float* out = (float*)d_out;

    char* ws = (char*)d_ws;
    int*   counts    = (int*)  (ws + 0);
    float* b2sum     = (float*)(ws + 1280);
    float* s_partial = (float*)(ws + 1536);
    float* w2sum     = (float*)(ws + 34304);
    int*   ptok      = (int*)  (ws + 99840);
    float* pscore    = (float*)(ws + 361984);
    int*   eidx      = (int*)  (ws + 624128);
    float* esc0      = (float*)(ws + 656896);
    float* esc1      = (float*)(ws + 689664);
    unsigned short* xb  = (unsigned short*)(ws + 722432);    // 8 MB
    unsigned short* w1f = (unsigned short*)(ws + 9111040);   // 16 MB

    prep_gate_k<<<8193, 256, 0, stream>>>(w1, w1f, w2, b2, w2sum, b2sum, counts,
                                          x, gw, gb, xb, eidx, esc0, esc1);
    route_k<<<NEXP, 1024, 0, stream>>>(eidx, esc0, esc1, b2sum, counts, ptok, pscore, s_partial);
    moe_gemm_k<<<dim3(135, 16), 256, 0, stream>>>(xb, w1f, b1, w2sum, counts, ptok, pscore, s_partial);
    lsm_k<<<NBAT, 256, 0, stream>>>(s_partial, out);
}

// Round 6
// 180.094 us; speedup vs baseline: 1.2334x; 1.2334x over previous
//
#include <hip/hip_runtime.h>
#include <hip/hip_bf16.h>
#include <math.h>

// Problem constants
#define T_TOK 8192   // B*S tokens
#define DIM   512    // D
#define NEXP  8      // E
#define HID   2048   // H
#define NBAT  8      // B
#define SEQ   1024   // S

typedef short  short8 __attribute__((ext_vector_type(8)));
typedef float  f32x4  __attribute__((ext_vector_type(4)));

__device__ __forceinline__ unsigned short f2bf(float f) {
    union { float f; unsigned int u; } v; v.f = f;
    unsigned int u = v.u;
    unsigned int r = u + 0x7FFFu + ((u >> 16) & 1u);  // RNE
    return (unsigned short)(r >> 16);
}

// tanh-approx gelu via single v_exp_f32: v * sigmoid(1.59577*(v + 0.044715 v^3))
__device__ __forceinline__ float gelu_f(float v) {
    float v2 = v * v;
    float w = v * (-2.302344f - 0.102955f * v2);   // -log2(e)*1.59577*(1 + 0.044715 v^2)
    return v / (1.f + __builtin_amdgcn_exp2f(w));
}

// ---------------- fused prep + gate ----
// w1f layout (fragment-direct): [E][G=128 hgrps of 16][KK=16 ksteps of 32][512 ushorts]
// block (e,g,kk): element (q*16+c)*8+j  =  w1[e][d=kk*32+q*8+j][h=g*16+c]
// -> GEMM lane (quad,col) reads its MFMA B-fragment at offset lane*8 (16B), fully coalesced.
__global__ void prep_gate_k(const float* __restrict__ w1, unsigned short* __restrict__ w1f,
                            const float* __restrict__ w2, const float* __restrict__ b2,
                            float* __restrict__ w2sum, float* __restrict__ b2sum,
                            int* __restrict__ counts,
                            const float* __restrict__ x, const float* __restrict__ gw,
                            const float* __restrict__ gb,
                            unsigned short* __restrict__ xb,
                            int* __restrict__ eidx, float* __restrict__ esc0,
                            float* __restrict__ esc1) {
    int bid = blockIdx.x;
    int tid = threadIdx.x;
    int wave = tid >> 6, lane = tid & 63;
    if (bid < 2048) {
        // ---- w1 [E][D][H] fp32 -> w1f fragment-direct bf16 ----
        __shared__ unsigned short tile[64][68];   // [hLocal][dLocal]
        int e = bid >> 8, r = bid & 255;
        int d0 = (r & 7) * 64, h0 = (r >> 3) * 64;
        const float* src = w1 + (size_t)e * DIM * HID;
        #pragma unroll
        for (int pass = 0; pass < 4; ++pass) {
            int dr = pass * 16 + (tid >> 4);
            int hc = (tid & 15) * 4;
            float4 v = *(const float4*)(src + (size_t)(d0 + dr) * HID + h0 + hc);
            tile[hc + 0][dr] = f2bf(v.x);
            tile[hc + 1][dr] = f2bf(v.y);
            tile[hc + 2][dr] = f2bf(v.z);
            tile[hc + 3][dr] = f2bf(v.w);
        }
        __syncthreads();
        // this 64x64 region covers ksteps {kk0,kk0+1} and hgrps {g0..g0+3}
        int l = tid & 63, q = l >> 4, c = l & 15;
        int kk0 = (r & 7) * 2, g0 = (r >> 3) * 4;
        #pragma unroll
        for (int pi = 0; pi < 2; ++pi) {
            int sub = pi * 4 + wave;            // 0..7
            int kk2 = sub >> 2, g2 = sub & 3;
            const unsigned short* tp = &tile[g2 * 16 + c][kk2 * 32 + q * 8];
            ushort4 a = *(const ushort4*)(tp);
            ushort4 b = *(const ushort4*)(tp + 4);
            unsigned short* dst = w1f +
                ((size_t)(e * 128 + g0 + g2) * 16 + kk0 + kk2) * 512 + l * 8;
            *(ushort4*)(dst)     = a;
            *(ushort4*)(dst + 4) = b;
        }
    } else if (bid < 4096) {
        // ---- gating + fused x->bf16 cast (one token per wave) ----
        int t = (bid - 2048) * 4 + wave;
        const float* xp = x + (size_t)t * DIM;
        unsigned short* xbp = xb + (size_t)t * DIM;
        float acc[8] = {0, 0, 0, 0, 0, 0, 0, 0};
        #pragma unroll
        for (int it = 0; it < 8; ++it) {
            int d = it * 64 + lane;
            float xv = xp[d];
            xbp[d] = f2bf(xv);
            float4 g0 = *(const float4*)(gw + d * 8);
            float4 g1 = *(const float4*)(gw + d * 8 + 4);
            acc[0] += xv * g0.x; acc[1] += xv * g0.y; acc[2] += xv * g0.z; acc[3] += xv * g0.w;
            acc[4] += xv * g1.x; acc[5] += xv * g1.y; acc[6] += xv * g1.z; acc[7] += xv * g1.w;
        }
        #pragma unroll
        for (int e = 0; e < 8; ++e) {
            float s = acc[e];
            #pragma unroll
            for (int off = 32; off >= 1; off >>= 1) s += __shfl_xor(s, off);
            acc[e] = s + gb[e];
        }
        float v0 = -1e30f, v1 = -1e30f; int i0 = 0, i1 = 0;
        #pragma unroll
        for (int e = 0; e < 8; ++e) {
            float v = acc[e];
            if (v > v0) { v1 = v0; i1 = i0; v0 = v; i0 = e; }
            else if (v > v1) { v1 = v; i1 = e; }
        }
        float e1 = expf(v1 - v0);
        float inv = 1.f / (1.f + e1);
        if (lane == 0) {
            eidx[t] = i0 | (i1 << 4);
            esc0[t] = inv;
            esc1[t] = e1 * inv;
        }
    } else if (bid < 8192) {
        // ---- w2sum: row-sums of w2 ----
        int row = (bid - 4096) * 4 + wave;
        const float* p = w2 + (size_t)row * DIM;
        float4 a = *(const float4*)(p + lane * 4);
        float4 b = *(const float4*)(p + 256 + lane * 4);
        float s = a.x + a.y + a.z + a.w + b.x + b.y + b.z + b.w;
        #pragma unroll
        for (int off = 32; off >= 1; off >>= 1) s += __shfl_xor(s, off);
        if (lane == 0) w2sum[row] = s;
    } else {
        if (tid < 8) counts[tid] = 0;
        for (int r = wave; r < NEXP; r += 4) {
            const float* p = b2 + (size_t)r * DIM;
            float s = 0.f;
            for (int i = lane; i < DIM; i += 64) s += p[i];
            #pragma unroll
            for (int off = 32; off >= 1; off >>= 1) s += __shfl_xor(s, off);
            if (lane == 0) b2sum[r] = s;
        }
    }
}

// ---------------- routing: ballot-rank within wave, LDS across waves, 8 atomics/block ----------------
__global__ __launch_bounds__(1024) void route_k(
    const int* __restrict__ eidx, const float* __restrict__ esc0,
    const float* __restrict__ esc1, const float* __restrict__ b2sum,
    int* __restrict__ counts,
    int* __restrict__ ptok, float* __restrict__ pscore,
    float* __restrict__ s_partial) {
    int tid = threadIdx.x;
    int t = blockIdx.x * 1024 + tid;
    int wv = tid >> 6, lane = tid & 63;
    int pk = eidx[t];
    int i0 = pk & 0xf, i1 = (pk >> 4) & 0xf;
    float s0 = esc0[t], s1 = esc1[t];

    s_partial[t] = s0 * b2sum[i0] + s1 * b2sum[i1];

    __shared__ int waveCnt[16][8];
    __shared__ int waveBase[16][8];

    unsigned long long m0[8], m1[8];
    #pragma unroll
    for (int e = 0; e < 8; ++e) {
        m0[e] = __ballot(i0 == e);
        m1[e] = __ballot(i1 == e);
    }
    if (lane < 8) {
        int c = 0;
        #pragma unroll
        for (int e = 0; e < 8; ++e)
            if (lane == e) c = __popcll(m0[e]) + __popcll(m1[e]);
        waveCnt[wv][lane] = c;
    }
    __syncthreads();
    if (tid < 8) {
        int e = tid;
        int total = 0;
        #pragma unroll
        for (int w = 0; w < 16; ++w) total += waveCnt[w][e];
        int base = atomicAdd(&counts[e], total);
        int run = base;
        #pragma unroll
        for (int w = 0; w < 16; ++w) {
            waveBase[w][e] = run;
            run += waveCnt[w][e];
        }
    }
    __syncthreads();

    unsigned long long lt = (1ULL << lane) - 1ULL;
    int slot0 = 0, slot1 = 0;
    #pragma unroll
    for (int e = 0; e < 8; ++e) {
        if (i0 == e) slot0 = waveBase[wv][e] + __popcll(m0[e] & lt);
        if (i1 == e) slot1 = waveBase[wv][e] + __popcll(m0[e]) + __popcll(m1[e] & lt);
    }
    ptok[i0 * T_TOK + slot0] = t;  pscore[i0 * T_TOK + slot0] = s0;
    ptok[i1 * T_TOK + slot1] = t;  pscore[i1 * T_TOK + slot1] = s1;
}

// ---------------- grouped GEMM: BK=64, A-only LDS dbuf, B global->VGPR dual-set,
// occupancy 3 (170 regs): af0/af1 + bf0/bf1 all live -> both B halves prefetched a
// full MFMA cluster ahead; A staged at distance 2 with exact counted vmcnt.
#define GPTR(p) (const __attribute__((address_space(1))) void*)(p)
#define LPTR(p) (__attribute__((address_space(3))) void*)(p)

__global__ __launch_bounds__(256, 3) void moe_gemm_k(
    const unsigned short* __restrict__ xb, const unsigned short* __restrict__ w1f,
    const float* __restrict__ b1, const float* __restrict__ w2sum,
    const int* __restrict__ counts, const int* __restrict__ ptok,
    const float* __restrict__ pscore, float* __restrict__ s_partial) {

    // XCD swizzle, hTile-pair ordering: xcd = flat&7 owns hTiles {2*xcd, 2*xcd+1};
    // consecutive blocks on an XCD share bx (A-tile L2 reuse); B slice 2MB < 4MB L2.
    int flat = blockIdx.x + (int)blockIdx.y * 135;
    int xcd = flat & 7;
    int s = flat >> 3;            // 0..269
    int bx = s >> 1;              // 0..134
    int hBase = (xcd * 2 + (s & 1)) * 128;

    // derive (expert, rowBase) from counts prefix
    int e = 8, rowBase = 0, accT = 0;
    #pragma unroll
    for (int i = 0; i < 8; ++i) {
        int nt = (counts[i] + 127) >> 7;
        if (e == 8 && bx < accT + nt) { e = i; rowBase = (bx - accT) * 128; }
        accT += nt;
    }
    if (e == 8) return;
    int n_e = counts[e];

    __shared__ unsigned short A_s[2][128 * 64];   // [buf][row][k], chunk-swizzled (proven 0-conflict)
    __shared__ int   tokLds[128];
    __shared__ float scoreLds[128];

    int tid = threadIdx.x;
    int wave = tid >> 6, lane = tid & 63;

    if (tid < 128) {
        int r = rowBase + tid;
        bool valid = r < n_e;
        tokLds[tid]   = valid ? ptok[e * T_TOK + r]   : 0;
        scoreLds[tid] = valid ? pscore[e * T_TOK + r] : 0.f;
    }
    __syncthreads();

    // A staging: 1024 linear 16B chunks per 128x64 tile; 4 per thread.
    // chunk c: row=c>>3, pos=c&7, global k-piece j=(pos^(row&7))*8.
    unsigned gAo[4];
    #pragma unroll
    for (int i = 0; i < 4; ++i) {
        int c = i * 256 + tid;                  // 0..1023
        int row = c >> 3, pos = c & 7;
        int j = (pos ^ (row & 7)) * 8;
        gAo[i] = (unsigned)tokLds[row] * DIM + j;
    }

    int wm = wave >> 1, wn = wave & 1;
    int quad = lane >> 4, col = lane & 15;

    f32x4 acc[4][4];
    #pragma unroll
    for (int m = 0; m < 4; ++m)
        #pragma unroll
        for (int n = 0; n < 4; ++n)
            acc[m][n] = (f32x4){0.f, 0.f, 0.f, 0.f};

    // A read addressing (both k-halves), m-stride = 16 rows * 64 = 1024 ushorts
    int aOff0 = (wm * 64 + col) * 64 + ((((0 << 2) | quad) ^ (col & 7)) * 8);
    int aOff1 = (wm * 64 + col) * 64 + ((((1 << 2) | quad) ^ (col & 7)) * 8);

    // B: fragment-direct; frag n at hgrp (hBase>>4)+wn*4+n; k-sub s at +s*512
    const unsigned short* bp = w1f +
        (size_t)(e * 128 + (hBase >> 4) + wn * 4) * 8192 + lane * 8;
    short8 bf0[4], bf1[4];

    // ---- prologue: stage A(0), A(1), load B(0,h0). Issue order pinned for vmcnt math.
    #pragma unroll
    for (int i = 0; i < 4; ++i)
        __builtin_amdgcn_global_load_lds(GPTR(xb + gAo[i]), LPTR(&A_s[0][i * 2048 + tid * 8]), 16, 0, 0);
    __builtin_amdgcn_sched_barrier(0);
    #pragma unroll
    for (int i = 0; i < 4; ++i)
        __builtin_amdgcn_global_load_lds(GPTR(xb + gAo[i] + 64), LPTR(&A_s[1][i * 2048 + tid * 8]), 16, 0, 0);
    __builtin_amdgcn_sched_barrier(0);
    #pragma unroll
    for (int n = 0; n < 4; ++n) bf0[n] = *(const short8*)(bp + n * 8192);
    __builtin_amdgcn_sched_barrier(0);

    #pragma unroll
    for (int kk = 0; kk < 8; ++kk) {
        const int cur = kk & 1;
        // exact newer-than-A(kk) VMEM counts (issue order pinned): kk0=8, kk7=12, else 16
        if (kk == 0)      { asm volatile("s_waitcnt vmcnt(8)"  ::: "memory"); }
        else if (kk == 7) { asm volatile("s_waitcnt vmcnt(12)" ::: "memory"); }
        else              { asm volatile("s_waitcnt vmcnt(16)" ::: "memory"); }
        __builtin_amdgcn_s_barrier();

        // issue B(kk, h1) early — covered by stage + MFMA half0
        #pragma unroll
        for (int n = 0; n < 4; ++n)
            bf1[n] = *(const short8*)(bp + (2 * kk + 1) * 512 + n * 8192);

        // read BOTH k-halves of A before releasing the buffer
        short8 af0[4], af1[4];
        const unsigned short* aB = &A_s[cur][0];
        #pragma unroll
        for (int m = 0; m < 4; ++m) af0[m] = *(const short8*)(aB + aOff0 + m * 1024);
        #pragma unroll
        for (int m = 0; m < 4; ++m) af1[m] = *(const short8*)(aB + aOff1 + m * 1024);
        asm volatile("s_waitcnt lgkmcnt(0)" ::: "memory");
        __builtin_amdgcn_s_barrier();

        // stage A(kk+2) into the just-released buffer
        if (kk < 6) {
            int ko = (kk + 2) * 64;
            #pragma unroll
            for (int i = 0; i < 4; ++i)
                __builtin_amdgcn_global_load_lds(GPTR(xb + gAo[i] + ko), LPTR(&A_s[cur][i * 2048 + tid * 8]), 16, 0, 0);
        }
        __builtin_amdgcn_sched_barrier(0);      // pin stage issue ahead of MFMA cluster

        // half 0: af0 x B(kk,h0)
        __builtin_amdgcn_s_setprio(1);
        #pragma unroll
        for (int m = 0; m < 4; ++m)
            #pragma unroll
            for (int n = 0; n < 4; ++n)
                acc[m][n] = __builtin_amdgcn_mfma_f32_16x16x32_bf16(af0[m], bf0[n], acc[m][n], 0, 0, 0);
        __builtin_amdgcn_s_setprio(0);

        // prefetch B(kk+1, h0) into bf0 (WAR on bf0 after half-0 consumed it);
        // a full MFMA cluster (half 1) covers its L2 latency.
        if (kk < 7) {
            #pragma unroll
            for (int n = 0; n < 4; ++n)
                bf0[n] = *(const short8*)(bp + (2 * kk + 2) * 512 + n * 8192);
        }
        __builtin_amdgcn_sched_barrier(0);

        // half 1: af1 x B(kk,h1)
        __builtin_amdgcn_s_setprio(1);
        #pragma unroll
        for (int m = 0; m < 4; ++m)
            #pragma unroll
            for (int n = 0; n < 4; ++n)
                acc[m][n] = __builtin_amdgcn_mfma_f32_16x16x32_bf16(af1[m], bf1[n], acc[m][n], 0, 0, 0);
        __builtin_amdgcn_s_setprio(0);
    }

    // epilogue: val = gelu(acc + b1[h]) * w2sum[h]; reduce over h; atomicAdd score*partial
    const float* b1e = b1 + e * HID;
    const float* w2e = w2sum + e * HID;
    float bias[4], wsum[4];
    #pragma unroll
    for (int n = 0; n < 4; ++n) {
        int h = hBase + wn * 64 + n * 16 + col;
        bias[n] = b1e[h];
        wsum[n] = w2e[h];
    }
    #pragma unroll
    for (int m = 0; m < 4; ++m) {
        float rp0 = 0.f, rp1 = 0.f, rp2 = 0.f, rp3 = 0.f;
        #pragma unroll
        for (int n = 0; n < 4; ++n) {
            rp0 += gelu_f(acc[m][n][0] + bias[n]) * wsum[n];
            rp1 += gelu_f(acc[m][n][1] + bias[n]) * wsum[n];
            rp2 += gelu_f(acc[m][n][2] + bias[n]) * wsum[n];
            rp3 += gelu_f(acc[m][n][3] + bias[n]) * wsum[n];
        }
        #pragma unroll
        for (int off = 8; off >= 1; off >>= 1) {
            rp0 += __shfl_xor(rp0, off);
            rp1 += __shfl_xor(rp1, off);
            rp2 += __shfl_xor(rp2, off);
            rp3 += __shfl_xor(rp3, off);
        }
        if (col < 4) {
            float mine = (col == 0) ? rp0 : (col == 1) ? rp1 : (col == 2) ? rp2 : rp3;
            int rl = wm * 64 + m * 16 + quad * 4 + col;
            int r = rowBase + rl;
            if (r < n_e)
                atomicAdd(&s_partial[tokLds[rl]], scoreLds[rl] * mine);
        }
    }
}

// ---------------- per-batch log_softmax over seq ----------------
__global__ void lsm_k(const float* __restrict__ s, float* __restrict__ out) {
    int b = blockIdx.x, tid = threadIdx.x;
    int wave = tid >> 6, lane = tid & 63;
    __shared__ float red[4];
    const float* sp = s + (size_t)b * SEQ;
    float v[4];
    #pragma unroll
    for (int i = 0; i < 4; ++i) v[i] = sp[tid + i * 256];
    float m = fmaxf(fmaxf(v[0], v[1]), fmaxf(v[2], v[3]));
    #pragma unroll
    for (int off = 32; off >= 1; off >>= 1) m = fmaxf(m, __shfl_xor(m, off));
    if (lane == 0) red[wave] = m;
    __syncthreads();
    m = fmaxf(fmaxf(red[0], red[1]), fmaxf(red[2], red[3]));
    __syncthreads();
    float t = 0.f;
    #pragma unroll
    for (int i = 0; i < 4; ++i) t += expf(v[i] - m);
    #pragma unroll
    for (int off = 32; off >= 1; off >>= 1) t += __shfl_xor(t, off);
    if (lane == 0) red[wave] = t;
    __syncthreads();
    t = red[0] + red[1] + red[2] + red[3];
    float L = m + logf(t);
    #pragma unroll
    for (int i = 0; i < 4; ++i) out[(size_t)b * SEQ + tid + i * 256] = v[i] - L;
}

extern "C" void kernel_launch(void* const* d_in, const int* in_sizes, int n_in,
                              void* d_out, int out_size, void* d_ws, size_t ws_size,
                              hipStream_t stream) {
    const float* x  = (const float*)d_in[0];
    const float* gw = (const float*)d_in[1];
    const float* gb = (const float*)d_in[2];
    const float* w1 = (const float*)d_in[3];
    const float* b1 = (const float*)d_in[4];
    const float* w2 = (const float*)d_in[5];
    const float* b2 = (const float*)d_in[6];
    float* out = (float*)d_out;

    char* ws = (char*)d_ws;
    int*   counts    = (int*)  (ws + 0);
    float* b2sum     = (float*)(ws + 1280);
    float* s_partial = (float*)(ws + 1536);
    float* w2sum     = (float*)(ws + 34304);
    int*   ptok      = (int*)  (ws + 99840);
    float* pscore    = (float*)(ws + 361984);
    int*   eidx      = (int*)  (ws + 624128);
    float* esc0      = (float*)(ws + 656896);
    float* esc1      = (float*)(ws + 689664);
    unsigned short* xb  = (unsigned short*)(ws + 722432);    // 8 MB
    unsigned short* w1f = (unsigned short*)(ws + 9111040);   // 16 MB

    prep_gate_k<<<8193, 256, 0, stream>>>(w1, w1f, w2, b2, w2sum, b2sum, counts,
                                          x, gw, gb, xb, eidx, esc0, esc1);
    route_k<<<NEXP, 1024, 0, stream>>>(eidx, esc0, esc1, b2sum, counts, ptok, pscore, s_partial);
    moe_gemm_k<<<dim3(135, 16), 256, 0, stream>>>(xb, w1f, b1, w2sum, counts, ptok, pscore, s_partial);
    lsm_k<<<NBAT, 256, 0, stream>>>(s_partial, out);
}